// Round 10
// baseline (149.692 us; speedup 1.0000x reference)
//
#include <hip/hip_runtime.h>
#include <math.h>

#define NPTS 4096
#define NEPS 4.096e-4f                 // 4096 * 1e-7
#define E2   7.3890560989306495f       // exp(2)

typedef float  f32x4 __attribute__((ext_vector_type(4)));
typedef short  s16x8 __attribute__((ext_vector_type(8)));

static __device__ __forceinline__ unsigned short f2b(float x) {
    unsigned u = __builtin_bit_cast(unsigned, x);
    return (unsigned short)((u + 0x7fffu + ((u >> 16) & 1u)) >> 16);
}
static __device__ __forceinline__ float b2f(unsigned short h) {
    return __builtin_bit_cast(float, (unsigned)h << 16);
}

// fragment-order (swizzled) element offset for element (r,c) of an R-row matrix
static __device__ __forceinline__ size_t swz(int r, int c, int R16) {
    return (((size_t)((c >> 5) * R16 + (r >> 4))) << 9)
         + ((size_t)((r & 15) + (((c & 31) >> 3) << 4)) << 3) + (c & 7);
}

// ---------------------------------------------------------------------------
// prep: f32 -> bf16 fragment-order converts + rpn W1 pads + bias + deltas + zero
// ---------------------------------------------------------------------------
__global__ __launch_bounds__(256) void prep_kernel(
    const float* __restrict__ roi_feat, const float* __restrict__ W_roi_feat,
    const float* __restrict__ roi_cls_W1,
    const float* __restrict__ rpn_feat, const float* __restrict__ W_rpn_feat,
    const float* __restrict__ rpn_cls_W1, const float* __restrict__ rpn_bbox_W1,
    const float* __restrict__ rpn_cls_b1, const float* __restrict__ rpn_bbox_b1,
    const float* __restrict__ roi_del, const float* __restrict__ rpn_del,
    unsigned short* __restrict__ roi_feat_sw, unsigned short* __restrict__ W_roi_feat_sw,
    unsigned short* __restrict__ roi_W1_sw,
    unsigned short* __restrict__ rpn_feat_sw, unsigned short* __restrict__ W_rpn_feat_sw,
    unsigned short* __restrict__ rpn_cW1_sw, unsigned short* __restrict__ rpn_bW1_sw,
    unsigned short* __restrict__ Db_roi, unsigned short* __restrict__ Db_rpn,
    float* __restrict__ bias_pad_c, float* __restrict__ bias_pad_b,
    float* __restrict__ out)
{
    const int b = blockIdx.x, t = threadIdx.x;
    if (b < 3776) {
        const float* in; unsigned short* o; int base, cshift, R16;
        if      (b < 2048) { in = roi_feat;   o = roi_feat_sw;   base = b;        cshift = 10; R16 = 256; }
        else if (b < 3072) { in = W_roi_feat; o = W_roi_feat_sw; base = b - 2048; cshift = 10; R16 = 128; }
        else if (b < 3200) { in = roi_cls_W1; o = roi_W1_sw;     base = b - 3072; cshift = 10; R16 = 16;  }
        else if (b < 3712) { in = rpn_feat;   o = rpn_feat_sw;   base = b - 3200; cshift = 8;  R16 = 256; }
        else               { in = W_rpn_feat; o = W_rpn_feat_sw; base = b - 3712; cshift = 8;  R16 = 32;  }
        const int i = base * 2048 + t * 8;
        const int r = i >> cshift, c = i & ((1 << cshift) - 1);
        const float4 v0 = *(const float4*)&in[i];
        const float4 v1 = *(const float4*)&in[i + 4];
        s16x8 pk;
        pk[0] = (short)f2b(v0.x); pk[1] = (short)f2b(v0.y);
        pk[2] = (short)f2b(v0.z); pk[3] = (short)f2b(v0.w);
        pk[4] = (short)f2b(v1.x); pk[5] = (short)f2b(v1.y);
        pk[6] = (short)f2b(v1.z); pk[7] = (short)f2b(v1.w);
        *(s16x8*)(o + swz(r, c, R16)) = pk;
    } else if (b < 3808) {
        const bool cls = b < 3792;
        const float* W = cls ? rpn_cls_W1 : rpn_bbox_W1;
        unsigned short* o = cls ? rpn_cW1_sw : rpn_bW1_sw;
        const int local = b - (cls ? 3776 : 3792);
        const int i = local * 2048 + t * 8;
        const int r = i >> 8, c = i & 255;
        s16x8 pk;
#pragma unroll
        for (int u = 0; u < 8; ++u)
            pk[u] = (r < 64) ? (short)f2b(W[r * 256 + c + u]) : (short)0;
        *(s16x8*)(o + swz(r, c, 8)) = pk;
    } else if (b == 3808) {
        if (t < 128)      bias_pad_c[t] = (t < 64) ? rpn_cls_b1[t] : 0.f;
        else              bias_pad_b[t - 128] = ((t - 128) < 64) ? rpn_bbox_b1[t - 128] : 0.f;
        if (t < 4) out[184 + t] = 0.f;
    } else {
        const int row = (b - 3809) * 256 + t;
        const int mat = row >> 12, r = row & 4095;
        const float* D = mat ? rpn_del : roi_del;
        unsigned short* o = mat ? Db_rpn : Db_roi;
        const float4 dv = *(const float4*)&D[(size_t)r * 4];
        ushort4 d4; d4.x = f2b(dv.x); d4.y = f2b(dv.y); d4.z = f2b(dv.z); d4.w = f2b(dv.w);
        unsigned short* p = o + (size_t)r * 32;
        ushort4 z4 = {0, 0, 0, 0};
        *(ushort4*)p = d4;
        *(ushort4*)(p + 4)  = z4;
        *(ushort4*)(p + 8)  = z4; *(ushort4*)(p + 12) = z4;
        *(ushort4*)(p + 16) = z4; *(ushort4*)(p + 20) = z4;
        *(ushort4*)(p + 24) = z4; *(ushort4*)(p + 28) = z4;
    }
}

// ---------------------------------------------------------------------------
// Register-direct MFMA GEMM, depth-4 pipeline (unchanged from R9)
// ---------------------------------------------------------------------------
struct GemmJob {
    const unsigned short *A, *W;
    unsigned short *C;
    const float *bias;
    const float *del, *Wd, *bd, *sc, *Wsc, *bs;
    int strideA, strideB;
    int M16;
    int ldc;
    int K, nbx, bstart;
};
struct GemmJobs { GemmJob j[4]; int n; };

#define LDSET(Av, Bv)                                          \
    {                                                          \
        _Pragma("unroll")                                      \
        for (int m = 0; m < 4; ++m) {                          \
            Av[m] = *(const s16x8*)(pa + (m << 9));            \
            Bv[m] = *(const s16x8*)(pb + (m << 9));            \
        }                                                      \
        pa += jb.strideA; pb += jb.strideB;                    \
    }

#define MMSET(Av, Bv)                                          \
    {                                                          \
        _Pragma("unroll")                                      \
        for (int m = 0; m < 4; ++m)                            \
            _Pragma("unroll")                                  \
            for (int n = 0; n < 4; ++n)                        \
                acc[m][n] = __builtin_amdgcn_mfma_f32_16x16x32_bf16( \
                    Av[m], Bv[n], acc[m][n], 0, 0, 0);         \
    }

template<bool EXTRAS, bool CSWZ, bool RELU>
__global__ __launch_bounds__(256) void gemm_reg(GemmJobs jobs)
{
    const int bid = blockIdx.x;
    int ji = 0;
#pragma unroll
    for (int i = 1; i < 4; ++i)
        if (i < jobs.n && bid >= jobs.j[i].bstart) ji = i;
    const GemmJob jb = jobs.j[ji];
    int local = bid - jb.bstart;
    const int nb = jb.nbx << 5;
    local = (local & 7) * (nb >> 3) + (local >> 3);
    const int bx = local % jb.nbx, by = local / jb.nbx;

    const int t = threadIdx.x, l = t & 63, w = t >> 6;
    const int wr = w >> 1, wc = w & 1;
    const int fr = l & 15, fq = l >> 4;

    const int sA0 = by * 8 + wr * 4;
    const int sB0 = bx * 8 + wc * 4;
    const unsigned short* pa = jb.A + ((size_t)sA0 << 9) + (size_t)(l * 8);
    const unsigned short* pb = jb.W + ((size_t)sB0 << 9) + (size_t)(l * 8);

    f32x4 acc[4][4] = {};
    s16x8 A0[4], B0[4], A1[4], B1[4], A2[4], B2[4], A3[4], B3[4];

    const int niter = jb.K >> 5;
    LDSET(A0, B0);
    LDSET(A1, B1);
    LDSET(A2, B2);

    for (int it = 0; it < niter; it += 4) {
        if (it + 3 < niter) LDSET(A3, B3);
        MMSET(A0, B0);
        if (it + 4 < niter) LDSET(A0, B0);
        MMSET(A1, B1);
        if (it + 5 < niter) LDSET(A1, B1);
        MMSET(A2, B2);
        if (it + 6 < niter) LDSET(A2, B2);
        MMSET(A3, B3);
    }

#pragma unroll
    for (int n = 0; n < 4; ++n) {
        const int c = (sB0 + n) * 16 + fr;
        float cadd = jb.bias[c];
        float wd0 = 0.f, wd1 = 0.f, wd2 = 0.f, wd3 = 0.f, wscv = 0.f;
        if (EXTRAS) {
            cadd += jb.bd[c] + jb.bs[c];
            const float4 w4 = *(const float4*)&jb.Wd[c * 4];
            wd0 = w4.x; wd1 = w4.y; wd2 = w4.z; wd3 = w4.w;
            wscv = jb.Wsc[c];
        }
#pragma unroll
        for (int m = 0; m < 4; ++m) {
            const int si = sA0 + m;
            unsigned short* cp;
            if (CSWZ) {
                const int kj = c >> 5;
                cp = jb.C + (((size_t)(kj * jb.M16 + si)) << 9)
                   + (((size_t)((c & 31) >> 3)) << 7) + (c & 7);
            }
#pragma unroll
            for (int j = 0; j < 4; ++j) {
                const int rr = fq * 4 + j;
                const int row = si * 16 + rr;
                float v = acc[m][n][j] + cadd;
                if (EXTRAS) {
                    const float4 dm = *(const float4*)&jb.del[row * 4];
                    v += dm.x * wd0 + dm.y * wd1 + dm.z * wd2 + dm.w * wd3
                       + jb.sc[row] * wscv;
                }
                if (RELU) v = fmaxf(v, 0.f);
                if (CSWZ) cp[(size_t)rr << 3] = f2b(v);
                else      jb.C[(size_t)row * jb.ldc + c] = f2b(v);
            }
        }
    }
}

// ---------------------------------------------------------------------------
// alphas for all 4 matrices (unchanged from R9)
// ---------------------------------------------------------------------------
__global__ __launch_bounds__(256) void alphas_all(
    const unsigned short* __restrict__ h_rpn_c, const unsigned short* __restrict__ h_rpn_b,
    const unsigned short* __restrict__ h_roi_c, const unsigned short* __restrict__ h_roi_b,
    const float* __restrict__ W2_rc, const float* __restrict__ W2_rb,
    const float* __restrict__ W2_oc,
    const float* __restrict__ b2_rc, const float* __restrict__ b2_rb,
    const float* __restrict__ b2_oc,
    const int* __restrict__ iter_ptr,
    float* __restrict__ A_rpn_c, float* __restrict__ A_rpn_b,
    float* __restrict__ A_roi_c, float* __restrict__ A_roi_b,
    unsigned short* __restrict__ Ab_all)
{
    const int vrow = blockIdx.x * 4 + (threadIdx.x >> 6);
    const int mat = vrow >> 12, row = vrow & 4095;
    const unsigned short* H; const float *W2, *b2; float* Ao; int ldh, Hd;
    if (mat == 0)      { H = h_rpn_c; W2 = W2_rc; b2 = b2_rc; Ao = A_rpn_c; ldh = 128; Hd = 64; }
    else if (mat == 1) { H = h_rpn_b; W2 = W2_rb; b2 = b2_rb; Ao = A_rpn_b; ldh = 128; Hd = 64; }
    else if (mat == 2) { H = h_roi_c; W2 = W2_oc; b2 = b2_oc; Ao = A_roi_c; ldh = 256; Hd = 256; }
    else               { H = h_roi_b; W2 = W2_oc; b2 = b2_oc; Ao = A_roi_b; ldh = 256; Hd = 256; }

    const int l = threadIdx.x & 63;
    float acc[8] = {};
    for (int m = l * 4; m < Hd; m += 256) {
        const ushort4 h4 = *(const ushort4*)&H[(size_t)row * ldh + m];
        const float h0 = b2f(h4.x), h1 = b2f(h4.y), h2 = b2f(h4.z), h3 = b2f(h4.w);
#pragma unroll
        for (int o = 0; o < 8; ++o) {
            const float4 w4 = *(const float4*)&W2[o * Hd + m];
            acc[o] += h0 * w4.x + h1 * w4.y + h2 * w4.z + h3 * w4.w;
        }
    }
#pragma unroll
    for (int o = 0; o < 8; ++o)
        for (int off = 32; off; off >>= 1)
            acc[o] += __shfl_xor(acc[o], off, 64);

    const int it = *iter_ptr;
    const float temp = fmaxf(1.0f, 30.0f * (float)(90000 - it) / 90000.0f);
    float lg[8], mx = -1e30f;
#pragma unroll
    for (int o = 0; o < 8; ++o) { lg[o] = (acc[o] + b2[o]) / temp; mx = fmaxf(mx, lg[o]); }
    float s = 0.f;
#pragma unroll
    for (int o = 0; o < 8; ++o) { lg[o] = __expf(lg[o] - mx); s += lg[o]; }
    const float inv = 1.0f / s;
    if (l < 8) Ao[(size_t)row * 8 + l] = lg[l] * inv;
    unsigned short* Ab = Ab_all + (size_t)mat * 131072 + (size_t)row * 32;
    if (l == 0) {
        ushort4 o0, o1;
        o0.x = f2b(lg[0]*inv); o0.y = f2b(lg[1]*inv); o0.z = f2b(lg[2]*inv); o0.w = f2b(lg[3]*inv);
        o1.x = f2b(lg[4]*inv); o1.y = f2b(lg[5]*inv); o1.z = f2b(lg[6]*inv); o1.w = f2b(lg[7]*inv);
        *(ushort4*)Ab = o0; *(ushort4*)(Ab + 4) = o1;
    } else if (l < 4) {
        ushort4 z = {0,0,0,0};
        *(ushort4*)(Ab + l * 8)     = z;
        *(ushort4*)(Ab + l * 8 + 4) = z;
    }
}

// ---------------------------------------------------------------------------
// finale: k-split MFMA loss partials + means.  2052 blocks:
//   b < 2048: loss partials.  li = b>>9 (0=roi_cls,1=rpn_cls,2=roi_bbox,3=rpn_bbox)
//             local = b&511: jblk = local>>2 (32 j's), ksplit = local&3 (1024 k's)
//             writes part[(li*4096+j)*4 + ksplit][0..2] = (Sx, Cg/Sg, U)
//   b 2048..2050: column means; b 2051: per-class means of A_roi_c
// ---------------------------------------------------------------------------
__global__ __launch_bounds__(256) void finale_kernel(
    const unsigned short* __restrict__ Ab_all,
    const unsigned short* __restrict__ Db_roi, const unsigned short* __restrict__ Db_rpn,
    const float* __restrict__ A_roi_c, const float* __restrict__ A_rpn_c,
    const float* __restrict__ A_roi_b, const float* __restrict__ A_rpn_b,
    const int* __restrict__ roi_class, const int* __restrict__ rpn_class,
    float* __restrict__ part, float* __restrict__ out)
{
    const int b = blockIdx.x, t = threadIdx.x;
    const int w = t >> 6, l = t & 63;
    const int fr = l & 15, fq = l >> 4;

    if (b < 2048) {
        __shared__ float sh[4][2][16][3];
        const int li = b >> 9;
        const int local = b & 511;
        const int jblk = local >> 2, ksplit = local & 3;
        const int j0 = jblk * 32;
        const bool is_cls = li < 2;
        const int mat = (li == 0) ? 2 : (li == 1) ? 0 : (li == 2) ? 3 : 1;
        const unsigned short* Ab = Ab_all + (size_t)mat * 131072;
        const unsigned short* Db = (li == 2) ? Db_roi : Db_rpn;
        const int* cls = (li == 0) ? roi_class : rpn_class;

        s16x8 bj[2], dj[2];
        int cj[2];
#pragma unroll
        for (int jt = 0; jt < 2; ++jt) {
            const int j = j0 + jt * 16;
            bj[jt] = *(const s16x8*)&Ab[(size_t)(j + fr) * 32 + fq * 8];
            if (is_cls) cj[jt] = cls[j + fr];
            else        dj[jt] = *(const s16x8*)&Db[(size_t)(j + fr) * 32 + fq * 8];
        }

        float Sx[2] = {}, W2s[2] = {}, U[2] = {};
        const int kbase0 = ksplit * 1024 + w * 256;
        const f32x4 zc = {0.f, 0.f, 0.f, 0.f};

        for (int ch = 0; ch < 16; ++ch) {
            const int kb = kbase0 + ch * 16;
            const s16x8 afr = *(const s16x8*)&Ab[(size_t)(kb + fr) * 32 + fq * 8];
            if (is_cls) {
                const int4 ck = *(const int4*)&cls[kb + fq * 4];
                const int ckr[4] = {ck.x, ck.y, ck.z, ck.w};
#pragma unroll
                for (int jt = 0; jt < 2; ++jt) {
                    const f32x4 g = __builtin_amdgcn_mfma_f32_16x16x32_bf16(afr, bj[jt], zc, 0, 0, 0);
#pragma unroll
                    for (int r = 0; r < 4; ++r) {
                        const float gv = g[r];
                        Sx[jt] += __expf(2.f * gv);
                        const float wgt = (ckr[r] == cj[jt]) ? E2 : 1.0f;
                        U[jt] = fmaf(wgt, gv, U[jt]);
                        W2s[jt] += wgt;
                    }
                }
            } else {
                const s16x8 dfr = *(const s16x8*)&Db[(size_t)(kb + fr) * 32 + fq * 8];
#pragma unroll
                for (int jt = 0; jt < 2; ++jt) {
                    const f32x4 g  = __builtin_amdgcn_mfma_f32_16x16x32_bf16(afr, bj[jt], zc, 0, 0, 0);
                    const f32x4 gd = __builtin_amdgcn_mfma_f32_16x16x32_bf16(dfr, dj[jt], zc, 0, 0, 0);
#pragma unroll
                    for (int r = 0; r < 4; ++r) {
                        const float gv = g[r];
                        const float ed = __expf(2.f * gd[r]);
                        Sx[jt] += __expf(2.f * gv);
                        W2s[jt] += ed;
                        U[jt] = fmaf(ed, gv, U[jt]);
                    }
                }
            }
        }

        // combine the 4 fq k-row groups, then the 4 waves
#pragma unroll
        for (int jt = 0; jt < 2; ++jt) {
            float vx = Sx[jt], vg = W2s[jt], vu = U[jt];
            for (int off = 16; off <= 32; off <<= 1) {
                vx += __shfl_xor(vx, off, 64);
                vg += __shfl_xor(vg, off, 64);
                vu += __shfl_xor(vu, off, 64);
            }
            if (fq == 0) {
                sh[w][jt][fr][0] = vx; sh[w][jt][fr][1] = vg; sh[w][jt][fr][2] = vu;
            }
        }
        __syncthreads();
        if (t < 32) {
            const int jt = t >> 4, jl = t & 15;
            float vx = 0.f, vg = 0.f, vu = 0.f;
#pragma unroll
            for (int wv = 0; wv < 4; ++wv) {
                vx += sh[wv][jt][jl][0]; vg += sh[wv][jt][jl][1]; vu += sh[wv][jt][jl][2];
            }
            const int j = j0 + jt * 16 + jl;
            float* p = part + (((size_t)li * 4096 + j) * 4 + ksplit) * 3;
            p[0] = vx; p[1] = vg; p[2] = vu;
        }
    } else if (b < 2051) {
        __shared__ float S4[4][8];
        const float* A = (b == 2048) ? A_rpn_c : (b == 2049) ? A_rpn_b : A_roi_b;
        const int off0 = (b == 2048) ? 0 : (b == 2049) ? 8 : 176;
        float acc[8] = {};
        for (int r = t; r < NPTS; r += 256) {
            const float4 v0 = *(const float4*)&A[(size_t)r * 8];
            const float4 v1 = *(const float4*)&A[(size_t)r * 8 + 4];
            acc[0]+=v0.x; acc[1]+=v0.y; acc[2]+=v0.z; acc[3]+=v0.w;
            acc[4]+=v1.x; acc[5]+=v1.y; acc[6]+=v1.z; acc[7]+=v1.w;
        }
#pragma unroll
        for (int o = 0; o < 8; ++o) {
            float v = acc[o];
            for (int offs = 32; offs; offs >>= 1) v += __shfl_xor(v, offs, 64);
            if (l == 0) S4[w][o] = v;
        }
        __syncthreads();
        if (t < 8) {
            const float s = S4[0][t] + S4[1][t] + S4[2][t] + S4[3][t];
            out[off0 + t] = s * (1.f / 4096.f);
        }
    } else {
        __shared__ float S[20][8];
        __shared__ float cnt[20];
        if (t < 160) ((float*)S)[t] = 0.f;
        if (t < 20) cnt[t] = 0.f;
        __syncthreads();
        for (int r = t; r < NPTS; r += 256) {
            const int c = roi_class[r];
            atomicAdd(&cnt[c], 1.0f);
            const float4 v0 = *(const float4*)&A_roi_c[(size_t)r * 8];
            const float4 v1 = *(const float4*)&A_roi_c[(size_t)r * 8 + 4];
            atomicAdd(&S[c][0], v0.x); atomicAdd(&S[c][1], v0.y);
            atomicAdd(&S[c][2], v0.z); atomicAdd(&S[c][3], v0.w);
            atomicAdd(&S[c][4], v1.x); atomicAdd(&S[c][5], v1.y);
            atomicAdd(&S[c][6], v1.z); atomicAdd(&S[c][7], v1.w);
        }
        __syncthreads();
        if (t < 160) {
            const int c = t >> 3;
            out[16 + t] = S[c][t & 7] / fmaxf(cnt[c], 1.f);
        }
    }
}

// ---------------------------------------------------------------------------
// loss finisher: 4 blocks (one per loss). Combines 4 k-split partials per j,
// applies the log form, reduces 4096 j, writes out[184+li] directly.
// ---------------------------------------------------------------------------
__global__ __launch_bounds__(256) void loss_finish_kernel(
    const float* __restrict__ part, float* __restrict__ out)
{
    const int li = blockIdx.x, t = threadIdx.x;
    float s = 0.f;
#pragma unroll
    for (int u = 0; u < 16; ++u) {
        const int j = t * 16 + u;
        const float* p = part + ((size_t)li * 4096 + j) * 12;
        const float vx = p[0] + p[3] + p[6] + p[9];
        const float vg = p[1] + p[4] + p[7] + p[10];
        const float vu = p[2] + p[5] + p[8] + p[11];
        s += (2.f * vu - __logf(vx + NEPS) * vg) / (vg + NEPS);
    }
    for (int off = 32; off; off >>= 1) s += __shfl_xor(s, off, 64);
    __shared__ float red[4];
    if ((t & 63) == 0) red[t >> 6] = s;
    __syncthreads();
    if (t == 0) out[184 + li] = -(red[0] + red[1] + red[2] + red[3]) / 4096.f;
}

// ---------------------------------------------------------------------------
extern "C" void kernel_launch(void* const* d_in, const int* in_sizes, int n_in,
                              void* d_out, int out_size, void* d_ws, size_t ws_size,
                              hipStream_t stream)
{
    const float* rpn_feat  = (const float*)d_in[0];
    const float* rpn_del   = (const float*)d_in[1];
    const float* rpn_scale = (const float*)d_in[2];
    const float* roi_feat  = (const float*)d_in[3];
    const float* roi_del   = (const float*)d_in[4];
    const float* roi_scale = (const float*)d_in[5];
    const int*   rpn_class = (const int*)d_in[6];
    const int*   roi_class = (const int*)d_in[7];
    const float* W_rpn_feat = (const float*)d_in[8];  const float* b_rpn_feat = (const float*)d_in[9];
    const float* W_rpn_del  = (const float*)d_in[10]; const float* b_rpn_del  = (const float*)d_in[11];
    const float* W_rpn_sc   = (const float*)d_in[12]; const float* b_rpn_sc   = (const float*)d_in[13];
    const float* W_roi_feat = (const float*)d_in[14]; const float* b_roi_feat = (const float*)d_in[15];
    const float* W_roi_del  = (const float*)d_in[16]; const float* b_roi_del  = (const float*)d_in[17];
    const float* W_roi_sc   = (const float*)d_in[18]; const float* b_roi_sc   = (const float*)d_in[19];
    const float* rpn_cls_W1  = (const float*)d_in[20]; const float* rpn_cls_b1  = (const float*)d_in[21];
    const float* rpn_cls_W2  = (const float*)d_in[22]; const float* rpn_cls_b2  = (const float*)d_in[23];
    const float* rpn_bbox_W1 = (const float*)d_in[24]; const float* rpn_bbox_b1 = (const float*)d_in[25];
    const float* rpn_bbox_W2 = (const float*)d_in[26]; const float* rpn_bbox_b2 = (const float*)d_in[27];
    const float* roi_cls_W1  = (const float*)d_in[28]; const float* roi_cls_b1  = (const float*)d_in[29];
    const float* roi_cls_W2  = (const float*)d_in[30]; const float* roi_cls_b2  = (const float*)d_in[31];
    const int* iter_ptr = (const int*)d_in[32];
    float* out = (float*)d_out;
    char*  wsb = (char*)d_ws;

    // ---- workspace layout (byte offsets; layouts fragment-order) ----
    unsigned short* roi_feat_sw   = (unsigned short*)(wsb + 0);          // 4096x1024
    unsigned short* Ab_all        = (unsigned short*)(wsb + 0);          // 4 x 4096x32 (launch 4+)
    unsigned short* W_roi_feat_sw = (unsigned short*)(wsb + 8388608);    // 2048x1024 (dead after launch 2)
    float*          part          = (float*)(wsb + 8388608);             // 4x4096x4x3 (launch 5+)
    unsigned short* roi_sum_sw    = (unsigned short*)(wsb + 12582912);   // 4096x2048
    unsigned short* roi_W1_sw     = (unsigned short*)(wsb + 29360128);   // 256x1024
    unsigned short* h_roi_c       = (unsigned short*)(wsb + 29884416);   // 4096x256 linear
    unsigned short* h_roi_b       = (unsigned short*)(wsb + 31981568);   // 4096x256 linear
    unsigned short* rpn_feat_sw   = (unsigned short*)(wsb + 34078720);   // 4096x256
    unsigned short* W_rpn_feat_sw = (unsigned short*)(wsb + 36175872);   // 512x256
    unsigned short* rpn_sum_sw    = (unsigned short*)(wsb + 36438016);   // 4096x512
    unsigned short* rpn_cW1_sw    = (unsigned short*)(wsb + 40632320);   // 128x256 padded
    unsigned short* rpn_bW1_sw    = (unsigned short*)(wsb + 40697856);   // 128x256 padded
    unsigned short* h_rpn_c       = (unsigned short*)(wsb + 40763392);   // 4096x128 linear
    unsigned short* h_rpn_b       = (unsigned short*)(wsb + 41811968);   // 4096x128 linear
    float* bias_pad_c = (float*)(wsb + 42860544);                        // 128
    float* bias_pad_b = (float*)(wsb + 42861056);                        // 128
    float* A_rpn_c    = (float*)(wsb + 42861568);                        // 4096x8
    float* A_rpn_b    = (float*)(wsb + 42992640);
    float* A_roi_c    = (float*)(wsb + 43123712);
    float* A_roi_b    = (float*)(wsb + 43254784);
    unsigned short* Db_roi = (unsigned short*)(wsb + 43385856);          // 4096x32
    unsigned short* Db_rpn = (unsigned short*)(wsb + 43648000);          // 4096x32

    // ---- 1: prep ----
    prep_kernel<<<dim3(3841), 256, 0, stream>>>(
        roi_feat, W_roi_feat, roi_cls_W1, rpn_feat, W_rpn_feat,
        rpn_cls_W1, rpn_bbox_W1, rpn_cls_b1, rpn_bbox_b1,
        roi_del, rpn_del,
        roi_feat_sw, W_roi_feat_sw, roi_W1_sw, rpn_feat_sw, W_rpn_feat_sw,
        rpn_cW1_sw, rpn_bW1_sw, Db_roi, Db_rpn, bias_pad_c, bias_pad_b, out);

    // ---- 2: both big GEMMs (extras fused; C fragment-order) ----
    {
        GemmJobs js;
        js.n = 2;
        js.j[0] = { rpn_feat_sw, W_rpn_feat_sw, rpn_sum_sw, b_rpn_feat,
                    rpn_del, W_rpn_del, b_rpn_del, rpn_scale, W_rpn_sc, b_rpn_sc,
                    131072, 16384, 256, 0, 256, 4, 0 };
        js.j[1] = { roi_feat_sw, W_roi_feat_sw, roi_sum_sw, b_roi_feat,
                    roi_del, W_roi_del, b_roi_del, roi_scale, W_roi_sc, b_roi_sc,
                    131072, 65536, 256, 0, 1024, 16, 128 };
        js.j[2] = js.j[0]; js.j[3] = js.j[0];
        gemm_reg<true, true, false><<<dim3(640), 256, 0, stream>>>(js);
    }

    // ---- 3: all 4 hidden GEMMs (relu fused; C linear) ----
    {
        GemmJobs js;
        js.n = 4;
        js.j[0] = { rpn_sum_sw,           rpn_cW1_sw, h_rpn_c, bias_pad_c,
                    nullptr, nullptr, nullptr, nullptr, nullptr, nullptr,
                    131072, 4096, 0, 128, 256, 1, 0 };
        js.j[1] = { rpn_sum_sw + 1048576, rpn_bW1_sw, h_rpn_b, bias_pad_b,
                    nullptr, nullptr, nullptr, nullptr, nullptr, nullptr,
                    131072, 4096, 0, 128, 256, 1, 32 };
        js.j[2] = { roi_sum_sw,           roi_W1_sw, h_roi_c, roi_cls_b1,
                    nullptr, nullptr, nullptr, nullptr, nullptr, nullptr,
                    131072, 8192, 0, 256, 1024, 2, 64 };
        // reference bug: bbox half also uses roi_cls W1/b1 (and W2/b2 below)
        js.j[3] = { roi_sum_sw + 4194304, roi_W1_sw, h_roi_b, roi_cls_b1,
                    nullptr, nullptr, nullptr, nullptr, nullptr, nullptr,
                    131072, 8192, 0, 256, 1024, 2, 128 };
        gemm_reg<false, false, true><<<dim3(192), 256, 0, stream>>>(js);
    }

    // ---- 4: all 4 alphas (f32 + padded bf16) ----
    alphas_all<<<dim3(4096), 256, 0, stream>>>(
        h_rpn_c, h_rpn_b, h_roi_c, h_roi_b,
        rpn_cls_W2, rpn_bbox_W2, roi_cls_W2,
        rpn_cls_b2, rpn_bbox_b2, roi_cls_b2,
        iter_ptr, A_rpn_c, A_rpn_b, A_roi_c, A_roi_b, Ab_all);

    // ---- 5: k-split loss partials + means ----
    finale_kernel<<<dim3(2052), 256, 0, stream>>>(
        Ab_all, Db_roi, Db_rpn,
        A_roi_c, A_rpn_c, A_roi_b, A_rpn_b,
        roi_class, rpn_class, part, out);

    // ---- 6: loss finish ----
    loss_finish_kernel<<<dim3(4), 256, 0, stream>>>(part, out);
}